// Round 3
// baseline (85162.805 us; speedup 1.0000x reference)
//
#include <hip/hip_runtime.h>
#include <math.h>

#define NN 4096
#define KK 8
#define DD 512
#define HH 512
#define NB 512
#define TPB 512
#define TOT (NB * TPB)
#define MAXR 1024
#define NNHH ((size_t)NN * HH)

// ws layout (bytes)
#define OFF_CTRL 0                          // [0]=bar_cnt [1]=bar_gen
#define OFF_STATE (256)                     // int state[NN]  0=pending 1=active 2=done
#define OFF_CNT   (OFF_STATE + 4 * NN)      // int cntArr[MAXR]
#define OFF_RLEN  (OFF_CNT + 4 * MAXR)      // int rlenArr[MAXR]
#define OFF_LIST0 (OFF_RLEN + 4 * MAXR)     // int list0[NN] (packed i|lenL<<12|lenR<<16)
#define OFF_LIST1 (OFF_LIST0 + 4 * NN)      // int list1[NN]
#define OFF_XIDX  (OFF_LIST1 + 4 * NN)      // int xidx[2][9][NN]: input row per (side,substep,slot)
#define OFF_H     (OFF_XIDX + 4 * 2 * 9 * NN)   // float hbuf[2][2][NN][HH] (parity, side)
#define OFF_C     (OFF_H + 4 * 2 * 2 * NN * HH) // float cbuf[2][NN][HH]
#define WS_ZERO_BYTES OFF_LIST0

__device__ __forceinline__ float sigm(float x) { return 1.0f / (1.0f + __expf(-x)); }

// Sense-reversing grid barrier. CRITICAL: the spin uses RELAXED loads (no
// per-poll cache invalidate — an ACQUIRE poll invalidates the XCD L2 every
// iteration, chip-wide cache poison). One release fence on entry, one
// acquire fence on exit.
__device__ __forceinline__ void grid_barrier(int* bar) {
    __syncthreads();
    if (threadIdx.x == 0) {
        __builtin_amdgcn_fence(__ATOMIC_RELEASE, "agent");
        int g = __hip_atomic_load(bar + 1, __ATOMIC_RELAXED, __HIP_MEMORY_SCOPE_AGENT);
        int a = __hip_atomic_fetch_add(bar + 0, 1, __ATOMIC_RELAXED, __HIP_MEMORY_SCOPE_AGENT);
        if (a == NB - 1) {
            __hip_atomic_store(bar + 0, 0, __ATOMIC_RELAXED, __HIP_MEMORY_SCOPE_AGENT);
            __hip_atomic_store(bar + 1, g + 1, __ATOMIC_RELEASE, __HIP_MEMORY_SCOPE_AGENT);
        } else {
            while (__hip_atomic_load(bar + 1, __ATOMIC_RELAXED, __HIP_MEMORY_SCOPE_AGENT) == g)
                __builtin_amdgcn_s_sleep(8);
        }
        __builtin_amdgcn_fence(__ATOMIC_ACQUIRE, "agent");
    }
    __syncthreads();
}

__global__ void __launch_bounds__(TPB, 4)   // 4 waves/EU -> 2 blocks/CU, VGPR<=128
tree_lstm_kernel(const float* __restrict__ x0,
                 const float* __restrict__ Wl_ih, const float* __restrict__ Wl_hh,
                 const float* __restrict__ bl_ih, const float* __restrict__ bl_hh,
                 const float* __restrict__ Wr_ih, const float* __restrict__ Wr_hh,
                 const float* __restrict__ br_ih, const float* __restrict__ br_hh,
                 const float* __restrict__ W_enc, const float* __restrict__ b_enc,
                 const int* __restrict__ lch, const int* __restrict__ rch,
                 float* ctx, char* ws) {
    const int tid  = threadIdx.x;
    const int gtid = blockIdx.x * TPB + tid;
    const int wave = gtid >> 6;        // 0..4095
    const int lane = tid & 63;
    const int u    = wave & 511;       // hidden unit owned by this wave
    const int side = (wave >> 9) & 1;  // 0 = left chain, 1 = right chain
    const int p    = wave >> 10;       // 4-way slot split
    const int egrp = (wave >> 9) & 7;  // enc: 8-way slot split

    int*   bar     = (int*)(ws + OFF_CTRL);
    int*   state   = (int*)(ws + OFF_STATE);
    int*   cntArr  = (int*)(ws + OFF_CNT);
    int*   rlenArr = (int*)(ws + OFF_RLEN);
    int*   list0   = (int*)(ws + OFF_LIST0);
    int*   list1   = (int*)(ws + OFF_LIST1);
    int*   xidx    = (int*)(ws + OFF_XIDX);
    float* hbuf    = (float*)(ws + OFF_H);
    float* cbuf    = (float*)(ws + OFF_C);

    const float* Wih = side ? Wr_ih : Wl_ih;
    const float* Whh = side ? Wr_hh : Wl_hh;
    const float* bih = side ? br_ih : bl_ih;
    const float* bhh = side ? br_hh : bl_hh;

    // Wave-resident weights: 4 gate rows (ih + hh), lane l covers cols [8l,8l+8).
    float wih[4][8], whh[4][8], bsum[4];
#pragma unroll
    for (int g = 0; g < 4; ++g) {
        const size_t row = (size_t)g * HH + u;
        const float4 wa = *(const float4*)(Wih + row * DD + lane * 8);
        const float4 wb = *(const float4*)(Wih + row * DD + lane * 8 + 4);
        wih[g][0] = wa.x; wih[g][1] = wa.y; wih[g][2] = wa.z; wih[g][3] = wa.w;
        wih[g][4] = wb.x; wih[g][5] = wb.y; wih[g][6] = wb.z; wih[g][7] = wb.w;
        const float4 ha = *(const float4*)(Whh + row * HH + lane * 8);
        const float4 hb = *(const float4*)(Whh + row * HH + lane * 8 + 4);
        whh[g][0] = ha.x; whh[g][1] = ha.y; whh[g][2] = ha.z; whh[g][3] = ha.w;
        whh[g][4] = hb.x; whh[g][5] = hb.y; whh[g][6] = hb.z; whh[g][7] = hb.w;
        bsum[g] = bih[row] + bhh[row];
    }
    float wenc[16];
#pragma unroll
    for (int j = 0; j < 4; ++j) {
        const float4 t = *(const float4*)(W_enc + (size_t)u * (2 * HH) + lane * 16 + j * 4);
        wenc[j * 4 + 0] = t.x; wenc[j * 4 + 1] = t.y; wenc[j * 4 + 2] = t.z; wenc[j * 4 + 3] = t.w;
    }
    const float bencv = b_enc[u];

    int r = 0, doneSum = 0;
    while (doneSum < NN && r < MAXR - 2) {
        int* curList = (r & 1) ? list1 : list0;

        // phase A: activate nodes whose children are all done; precompute
        // per-substep input rows so the hot loop has no pointer chase.
        if (gtid < NN) {
            const int i = gtid;
            if (state[i] == 0) {
                bool ok = true;
                int ll = 1, lr = 1;
#pragma unroll
                for (int k = 0; k < KK; ++k) {
                    const int c = lch[i * KK + k];
                    if (c >= 0) { ll = k + 2; if (state[c] != 2) ok = false; }
                }
#pragma unroll
                for (int k = 0; k < KK; ++k) {
                    const int c = rch[i * KK + k];
                    if (c >= 0) { lr = k + 2; if (state[c] != 2) ok = false; }
                }
                if (ok) {
                    state[i] = 1;
                    const int pos = atomicAdd(&cntArr[r], 1);
                    curList[pos] = i | (ll << 12) | (lr << 16);
                    atomicMax(&rlenArr[r], ll > lr ? ll : lr);
                    xidx[(0 * 9 + 0) * NN + pos] = i;
                    xidx[(1 * 9 + 0) * NN + pos] = i;
#pragma unroll
                    for (int q = 1; q < 9; ++q) {
                        xidx[(0 * 9 + q) * NN + pos] = (q < ll) ? lch[i * KK + q - 1] : -1;
                        xidx[(1 * 9 + q) * NN + pos] = (q < lr) ? rch[i * KK + q - 1] : -1;
                    }
                }
            }
        }
        grid_barrier(bar);
        const int B = __hip_atomic_load(&cntArr[r], __ATOMIC_RELAXED, __HIP_MEMORY_SCOPE_AGENT);
        const int L = __hip_atomic_load(&rlenArr[r], __ATOMIC_RELAXED, __HIP_MEMORY_SCOPE_AGENT);
        doneSum += B;

        // lockstep chain sub-steps; h double-buffered by step parity
        for (int q = 0; q < L; ++q) {
            float*       hb_w = hbuf + (size_t)((q & 1) * 2 + side) * NNHH;
            const float* hb_r = hbuf + (size_t)(((q & 1) ^ 1) * 2 + side) * NNHH;
            float*       cb   = cbuf + (size_t)side * NNHH;
            const int*   xq   = xidx + (size_t)(side * 9 + q) * NN;
            const float* xbase = (q == 0) ? x0 : ctx;
            for (int s0 = p * 4; s0 < B; s0 += 16) {
                const int4 e4 = *(const int4*)(curList + s0);  // independent loads
                const int4 c4 = *(const int4*)(xq + s0);
                const int ei[4] = {e4.x, e4.y, e4.z, e4.w};
                const int ci[4] = {c4.x, c4.y, c4.z, c4.w};
                bool  act[4];
                float xr[4][8], hr[4][8], cp[4];
#pragma unroll
                for (int k = 0; k < 4; ++k)
                    act[k] = (s0 + k < B) && (ci[k] >= 0);
                // gather phase: all loads in flight before compute
#pragma unroll
                for (int k = 0; k < 4; ++k) {
                    if (!act[k]) continue;
                    const float* xv = xbase + (size_t)ci[k] * DD + lane * 8;
                    const float4 xa = *(const float4*)xv;
                    const float4 xb = *(const float4*)(xv + 4);
                    xr[k][0] = xa.x; xr[k][1] = xa.y; xr[k][2] = xa.z; xr[k][3] = xa.w;
                    xr[k][4] = xb.x; xr[k][5] = xb.y; xr[k][6] = xb.z; xr[k][7] = xb.w;
                    if (q > 0) {
                        const int i = ei[k] & 0xFFF;
                        const float* hv = hb_r + (size_t)i * HH + lane * 8;
                        const float4 hA = *(const float4*)hv;
                        const float4 hB = *(const float4*)(hv + 4);
                        hr[k][0] = hA.x; hr[k][1] = hA.y; hr[k][2] = hA.z; hr[k][3] = hA.w;
                        hr[k][4] = hB.x; hr[k][5] = hB.y; hr[k][6] = hB.z; hr[k][7] = hB.w;
                        cp[k] = cb[(size_t)i * HH + u];
                    } else cp[k] = 0.f;
                }
                // compute phase: 4 independent FMA+reduce chains
#pragma unroll
                for (int k = 0; k < 4; ++k) {
                    if (!act[k]) continue;
                    const int i = ei[k] & 0xFFF;
                    float a0 = 0.f, a1 = 0.f, a2 = 0.f, a3 = 0.f;
#pragma unroll
                    for (int j = 0; j < 8; ++j) {
                        a0 += wih[0][j] * xr[k][j];
                        a1 += wih[1][j] * xr[k][j];
                        a2 += wih[2][j] * xr[k][j];
                        a3 += wih[3][j] * xr[k][j];
                    }
                    if (q > 0) {
#pragma unroll
                        for (int j = 0; j < 8; ++j) {
                            a0 += whh[0][j] * hr[k][j];
                            a1 += whh[1][j] * hr[k][j];
                            a2 += whh[2][j] * hr[k][j];
                            a3 += whh[3][j] * hr[k][j];
                        }
                    }
                    // merge butterfly: lane l ends holding gate (l&3)'s sum
                    float v01, v23, v;
                    {
                        const bool hi = lane & 1;
                        float keep = hi ? a1 : a0, send = hi ? a0 : a1;
                        v01 = keep + __shfl_xor(send, 1, 64);
                        keep = hi ? a3 : a2; send = hi ? a2 : a3;
                        v23 = keep + __shfl_xor(send, 1, 64);
                    }
                    {
                        const bool hi = lane & 2;
                        const float keep = hi ? v23 : v01, send = hi ? v01 : v23;
                        v = keep + __shfl_xor(send, 2, 64);
                    }
                    v += __shfl_xor(v, 4, 64);
                    v += __shfl_xor(v, 8, 64);
                    v += __shfl_xor(v, 16, 64);
                    v += __shfl_xor(v, 32, 64);
                    const float g1 = __shfl(v, 1, 64);
                    const float g2 = __shfl(v, 2, 64);
                    const float g3 = __shfl(v, 3, 64);
                    // valid on lane 0 (v there = gate i)
                    const float gi = v  + bsum[0];
                    const float gf = g1 + bsum[1];
                    const float gg = g2 + bsum[2];
                    const float go = g3 + bsum[3];
                    const float cn = sigm(gf) * cp[k] + sigm(gi) * tanhf(gg);
                    const float hn = sigm(go) * tanhf(cn);
                    if (lane == 0) {
                        cb[(size_t)i * HH + u]   = cn;
                        hb_w[(size_t)i * HH + u] = hn;
                    }
                }
            }
            grid_barrier(bar);
        }

        // enc: ctx[i][u] = tanh(W_enc[u] . [hl|hr] + b_enc[u]); per-side parity
        if (B > 0) {
            const int lhalf = lane >> 5;          // 0 -> hl, 1 -> hr
            const int col   = (lane * 16) & 511;
            for (int slot = egrp; slot < B; slot += 8) {
                const int e   = curList[slot];
                const int i   = e & 0xFFF;
                const int len = (e >> (12 + 4 * lhalf)) & 0xF;
                const float* hv = hbuf + (size_t)(((len - 1) & 1) * 2 + lhalf) * NNHH
                                + (size_t)i * HH + col;
                float acc = 0.f;
#pragma unroll
                for (int j = 0; j < 4; ++j) {
                    const float4 t = *(const float4*)(hv + j * 4);
                    acc += wenc[j * 4 + 0] * t.x + wenc[j * 4 + 1] * t.y +
                           wenc[j * 4 + 2] * t.z + wenc[j * 4 + 3] * t.w;
                }
#pragma unroll
                for (int m = 1; m < 64; m <<= 1) acc += __shfl_xor(acc, m, 64);
                if (lane == 0) {
                    ctx[(size_t)i * DD + u] = tanhf(acc + bencv);
                    if (u == 0) state[i] = 2;   // node done; visible next round
                }
            }
        }
        grid_barrier(bar);
        ++r;
    }
}

extern "C" void kernel_launch(void* const* d_in, const int* in_sizes, int n_in,
                              void* d_out, int out_size, void* d_ws, size_t ws_size,
                              hipStream_t stream) {
    hipMemsetAsync(d_ws, 0, WS_ZERO_BYTES, stream);
    tree_lstm_kernel<<<dim3(NB), dim3(TPB), 0, stream>>>(
        (const float*)d_in[0],
        (const float*)d_in[1], (const float*)d_in[2],
        (const float*)d_in[3], (const float*)d_in[4],
        (const float*)d_in[5], (const float*)d_in[6],
        (const float*)d_in[7], (const float*)d_in[8],
        (const float*)d_in[9], (const float*)d_in[10],
        (const int*)d_in[11], (const int*)d_in[12],
        (float*)d_out, (char*)d_ws);
}

// Round 4
// 20004.341 us; speedup vs baseline: 4.2572x; 4.2572x over previous
//
#include <hip/hip_runtime.h>
#include <math.h>

#define NN 4096
#define KK 8
#define DD 512
#define HH 512
#define NB 256
#define TPB 512
#define TOT (NB * TPB)
#define MAXR 1024
#define NNHH ((size_t)NN * HH)
#define NGRP 8
#define GRPSZ (NB / NGRP)

// ws layout (bytes)
#define OFF_CTRL 0                          // barrier control, 8192 B (see grid_barrier)
#define OFF_STATE 8192                      // int state[NN]  0=pending 1=active 2=done
#define OFF_CNT   (OFF_STATE + 4 * NN)      // int cntArr[MAXR]
#define OFF_RLEN  (OFF_CNT + 4 * MAXR)      // int rlenArr[MAXR]
#define OFF_LIST0 (OFF_RLEN + 4 * MAXR)     // int list0[NN] (packed i|lenL<<12|lenR<<16)
#define OFF_LIST1 (OFF_LIST0 + 4 * NN)      // int list1[NN]
#define OFF_XIDX  (OFF_LIST1 + 4 * NN)      // int xidx[2][9][NN]: input row per (side,substep,slot)
#define OFF_H     (OFF_XIDX + 4 * 2 * 9 * NN)   // float hbuf[2][2][NN][HH] (parity, side)
#define OFF_C     (OFF_H + 4 * 2 * 2 * NN * HH) // float cbuf[2][NN][HH]
#define WS_ZERO_BYTES OFF_LIST0

__device__ __forceinline__ float sigm(float x) { return 1.0f / (1.0f + __expf(-x)); }

// Two-level grid barrier. Single-counter barriers cost ~100us at NB=256:
// 256 serialized same-line cross-XCD atomic RMWs. Here arrivals spread over
// 8 cache-line-separated group counters (32 local atomics each, lines in
// parallel), 8 leaders hit the root, broadcast fans out through per-group
// gen flags (8 pollers/line). Gen is monotonic (target passed by caller);
// gen stores are RELEASE so counter resets can't reorder past them.
// Spin polls are RELAXED (an ACQUIRE poll invalidates caches every
// iteration — chip-wide poison). One release fence on entry, one acquire
// fence on exit.
__device__ __forceinline__ void grid_barrier(int* ctrl, int grp, int target) {
    __syncthreads();
    if (threadIdx.x == 0) {
        __builtin_amdgcn_fence(__ATOMIC_RELEASE, "agent");
        int* root_cnt = ctrl;            // line 0
        int* root_gen = ctrl + 64;       // line 1
        int* gcnt = ctrl + 128 + grp * 64;
        int* ggen = ctrl + 1024 + grp * 64;
        const int a = __hip_atomic_fetch_add(gcnt, 1, __ATOMIC_RELAXED, __HIP_MEMORY_SCOPE_AGENT);
        if (a == GRPSZ - 1) {
            __hip_atomic_store(gcnt, 0, __ATOMIC_RELAXED, __HIP_MEMORY_SCOPE_AGENT);
            const int aa = __hip_atomic_fetch_add(root_cnt, 1, __ATOMIC_RELAXED, __HIP_MEMORY_SCOPE_AGENT);
            if (aa == NGRP - 1) {
                __hip_atomic_store(root_cnt, 0, __ATOMIC_RELAXED, __HIP_MEMORY_SCOPE_AGENT);
                __hip_atomic_store(root_gen, target, __ATOMIC_RELEASE, __HIP_MEMORY_SCOPE_AGENT);
            } else {
                while (__hip_atomic_load(root_gen, __ATOMIC_RELAXED, __HIP_MEMORY_SCOPE_AGENT) != target)
                    __builtin_amdgcn_s_sleep(2);
            }
            __hip_atomic_store(ggen, target, __ATOMIC_RELEASE, __HIP_MEMORY_SCOPE_AGENT);
        } else {
            while (__hip_atomic_load(ggen, __ATOMIC_RELAXED, __HIP_MEMORY_SCOPE_AGENT) != target)
                __builtin_amdgcn_s_sleep(2);
        }
        __builtin_amdgcn_fence(__ATOMIC_ACQUIRE, "agent");
    }
    __syncthreads();
}

__global__ void __launch_bounds__(TPB, 2)   // VGPR cap 256: weight hoist MUST stay in regs
tree_lstm_kernel(const float* __restrict__ x0,
                 const float* __restrict__ Wl_ih, const float* __restrict__ Wl_hh,
                 const float* __restrict__ bl_ih, const float* __restrict__ bl_hh,
                 const float* __restrict__ Wr_ih, const float* __restrict__ Wr_hh,
                 const float* __restrict__ br_ih, const float* __restrict__ br_hh,
                 const float* __restrict__ W_enc, const float* __restrict__ b_enc,
                 const int* __restrict__ lch, const int* __restrict__ rch,
                 float* ctx, char* ws) {
    const int tid  = threadIdx.x;
    const int gtid = blockIdx.x * TPB + tid;
    const int wave = gtid >> 6;        // 0..2047
    const int lane = tid & 63;
    const int u    = wave & 511;       // hidden unit owned by this wave
    const int side = (wave >> 9) & 1;  // 0 = left chain, 1 = right chain
    const int p    = wave >> 10;       // 2-way slot split
    const int egrp = wave >> 9;        // enc: 4-way slot split
    const int bgrp = blockIdx.x & 7;   // barrier group (likely XCD-local)

    int*   ctrl    = (int*)(ws + OFF_CTRL);
    int*   state   = (int*)(ws + OFF_STATE);
    int*   cntArr  = (int*)(ws + OFF_CNT);
    int*   rlenArr = (int*)(ws + OFF_RLEN);
    int*   list0   = (int*)(ws + OFF_LIST0);
    int*   list1   = (int*)(ws + OFF_LIST1);
    int*   xidx    = (int*)(ws + OFF_XIDX);
    float* hbuf    = (float*)(ws + OFF_H);
    float* cbuf    = (float*)(ws + OFF_C);

    const float* Wih = side ? Wr_ih : Wl_ih;
    const float* Whh = side ? Wr_hh : Wl_hh;
    const float* bih = side ? br_ih : bl_ih;
    const float* bhh = side ? br_hh : bl_hh;

    // Wave-resident weights: 4 gate rows (ih + hh), lane l covers cols [8l,8l+8).
    float wih[4][8], whh[4][8], bsum[4];
#pragma unroll
    for (int g = 0; g < 4; ++g) {
        const size_t row = (size_t)g * HH + u;
        const float4 wa = *(const float4*)(Wih + row * DD + lane * 8);
        const float4 wb = *(const float4*)(Wih + row * DD + lane * 8 + 4);
        wih[g][0] = wa.x; wih[g][1] = wa.y; wih[g][2] = wa.z; wih[g][3] = wa.w;
        wih[g][4] = wb.x; wih[g][5] = wb.y; wih[g][6] = wb.z; wih[g][7] = wb.w;
        const float4 ha = *(const float4*)(Whh + row * HH + lane * 8);
        const float4 hb = *(const float4*)(Whh + row * HH + lane * 8 + 4);
        whh[g][0] = ha.x; whh[g][1] = ha.y; whh[g][2] = ha.z; whh[g][3] = ha.w;
        whh[g][4] = hb.x; whh[g][5] = hb.y; whh[g][6] = hb.z; whh[g][7] = hb.w;
        bsum[g] = bih[row] + bhh[row];
    }
    float wenc[16];
#pragma unroll
    for (int j = 0; j < 4; ++j) {
        const float4 t = *(const float4*)(W_enc + (size_t)u * (2 * HH) + lane * 16 + j * 4);
        wenc[j * 4 + 0] = t.x; wenc[j * 4 + 1] = t.y; wenc[j * 4 + 2] = t.z; wenc[j * 4 + 3] = t.w;
    }
    const float bencv = b_enc[u];

    int r = 0, doneSum = 0, bnum = 0;
    while (doneSum < NN && r < MAXR - 2) {
        int* curList = (r & 1) ? list1 : list0;

        // phase A: activate nodes whose children are all done; precompute
        // per-substep input rows so the hot loop has no pointer chase.
        if (gtid < NN) {
            const int i = gtid;
            if (state[i] == 0) {
                bool ok = true;
                int ll = 1, lr = 1;
#pragma unroll
                for (int k = 0; k < KK; ++k) {
                    const int c = lch[i * KK + k];
                    if (c >= 0) { ll = k + 2; if (state[c] != 2) ok = false; }
                }
#pragma unroll
                for (int k = 0; k < KK; ++k) {
                    const int c = rch[i * KK + k];
                    if (c >= 0) { lr = k + 2; if (state[c] != 2) ok = false; }
                }
                if (ok) {
                    state[i] = 1;
                    const int pos = atomicAdd(&cntArr[r], 1);
                    curList[pos] = i | (ll << 12) | (lr << 16);
                    atomicMax(&rlenArr[r], ll > lr ? ll : lr);
                    xidx[(0 * 9 + 0) * NN + pos] = i;
                    xidx[(1 * 9 + 0) * NN + pos] = i;
#pragma unroll
                    for (int q = 1; q < 9; ++q) {
                        xidx[(0 * 9 + q) * NN + pos] = (q < ll) ? lch[i * KK + q - 1] : -1;
                        xidx[(1 * 9 + q) * NN + pos] = (q < lr) ? rch[i * KK + q - 1] : -1;
                    }
                }
            }
        }
        grid_barrier(ctrl, bgrp, ++bnum);
        const int B = __hip_atomic_load(&cntArr[r], __ATOMIC_RELAXED, __HIP_MEMORY_SCOPE_AGENT);
        const int L = __hip_atomic_load(&rlenArr[r], __ATOMIC_RELAXED, __HIP_MEMORY_SCOPE_AGENT);
        doneSum += B;

        // lockstep chain sub-steps; h double-buffered by step parity
        for (int q = 0; q < L; ++q) {
            float*       hb_w = hbuf + (size_t)((q & 1) * 2 + side) * NNHH;
            const float* hb_r = hbuf + (size_t)(((q & 1) ^ 1) * 2 + side) * NNHH;
            float*       cb   = cbuf + (size_t)side * NNHH;
            const int*   xq   = xidx + (size_t)(side * 9 + q) * NN;
            const float* xbase = (q == 0) ? x0 : ctx;
            for (int s0 = p * 4; s0 < B; s0 += 8) {
                const int4 e4 = *(const int4*)(curList + s0);  // independent loads
                const int4 c4 = *(const int4*)(xq + s0);
                const int ei[4] = {e4.x, e4.y, e4.z, e4.w};
                const int ci[4] = {c4.x, c4.y, c4.z, c4.w};
                bool  act[4];
                float xr[4][8], hr[4][8], cp[4];
#pragma unroll
                for (int k = 0; k < 4; ++k)
                    act[k] = (s0 + k < B) && (ci[k] >= 0);
                // gather phase: all loads in flight before compute
#pragma unroll
                for (int k = 0; k < 4; ++k) {
                    if (!act[k]) continue;
                    const float* xv = xbase + (size_t)ci[k] * DD + lane * 8;
                    const float4 xa = *(const float4*)xv;
                    const float4 xb = *(const float4*)(xv + 4);
                    xr[k][0] = xa.x; xr[k][1] = xa.y; xr[k][2] = xa.z; xr[k][3] = xa.w;
                    xr[k][4] = xb.x; xr[k][5] = xb.y; xr[k][6] = xb.z; xr[k][7] = xb.w;
                    if (q > 0) {
                        const int i = ei[k] & 0xFFF;
                        const float* hv = hb_r + (size_t)i * HH + lane * 8;
                        const float4 hA = *(const float4*)hv;
                        const float4 hB = *(const float4*)(hv + 4);
                        hr[k][0] = hA.x; hr[k][1] = hA.y; hr[k][2] = hA.z; hr[k][3] = hA.w;
                        hr[k][4] = hB.x; hr[k][5] = hB.y; hr[k][6] = hB.z; hr[k][7] = hB.w;
                        cp[k] = cb[(size_t)i * HH + u];
                    } else cp[k] = 0.f;
                }
                // compute phase: 4 independent FMA+reduce chains
#pragma unroll
                for (int k = 0; k < 4; ++k) {
                    if (!act[k]) continue;
                    const int i = ei[k] & 0xFFF;
                    float a0 = 0.f, a1 = 0.f, a2 = 0.f, a3 = 0.f;
#pragma unroll
                    for (int j = 0; j < 8; ++j) {
                        a0 += wih[0][j] * xr[k][j];
                        a1 += wih[1][j] * xr[k][j];
                        a2 += wih[2][j] * xr[k][j];
                        a3 += wih[3][j] * xr[k][j];
                    }
                    if (q > 0) {
#pragma unroll
                        for (int j = 0; j < 8; ++j) {
                            a0 += whh[0][j] * hr[k][j];
                            a1 += whh[1][j] * hr[k][j];
                            a2 += whh[2][j] * hr[k][j];
                            a3 += whh[3][j] * hr[k][j];
                        }
                    }
                    // merge butterfly: lane l ends holding gate (l&3)'s sum
                    float v01, v23, v;
                    {
                        const bool hi = lane & 1;
                        float keep = hi ? a1 : a0, send = hi ? a0 : a1;
                        v01 = keep + __shfl_xor(send, 1, 64);
                        keep = hi ? a3 : a2; send = hi ? a2 : a3;
                        v23 = keep + __shfl_xor(send, 1, 64);
                    }
                    {
                        const bool hi = lane & 2;
                        const float keep = hi ? v23 : v01, send = hi ? v01 : v23;
                        v = keep + __shfl_xor(send, 2, 64);
                    }
                    v += __shfl_xor(v, 4, 64);
                    v += __shfl_xor(v, 8, 64);
                    v += __shfl_xor(v, 16, 64);
                    v += __shfl_xor(v, 32, 64);
                    const float g1 = __shfl(v, 1, 64);
                    const float g2 = __shfl(v, 2, 64);
                    const float g3 = __shfl(v, 3, 64);
                    // valid on lane 0 (v there = gate i)
                    const float gi = v  + bsum[0];
                    const float gf = g1 + bsum[1];
                    const float gg = g2 + bsum[2];
                    const float go = g3 + bsum[3];
                    const float cn = sigm(gf) * cp[k] + sigm(gi) * tanhf(gg);
                    const float hn = sigm(go) * tanhf(cn);
                    if (lane == 0) {
                        cb[(size_t)i * HH + u]   = cn;
                        hb_w[(size_t)i * HH + u] = hn;
                    }
                }
            }
            grid_barrier(ctrl, bgrp, ++bnum);
        }

        // enc: ctx[i][u] = tanh(W_enc[u] . [hl|hr] + b_enc[u]); per-side parity
        if (B > 0) {
            const int lhalf = lane >> 5;          // 0 -> hl, 1 -> hr
            const int col   = (lane * 16) & 511;
            for (int slot = egrp; slot < B; slot += 4) {
                const int e   = curList[slot];
                const int i   = e & 0xFFF;
                const int len = (e >> (12 + 4 * lhalf)) & 0xF;
                const float* hv = hbuf + (size_t)(((len - 1) & 1) * 2 + lhalf) * NNHH
                                + (size_t)i * HH + col;
                float acc = 0.f;
#pragma unroll
                for (int j = 0; j < 4; ++j) {
                    const float4 t = *(const float4*)(hv + j * 4);
                    acc += wenc[j * 4 + 0] * t.x + wenc[j * 4 + 1] * t.y +
                           wenc[j * 4 + 2] * t.z + wenc[j * 4 + 3] * t.w;
                }
#pragma unroll
                for (int m = 1; m < 64; m <<= 1) acc += __shfl_xor(acc, m, 64);
                if (lane == 0) {
                    ctx[(size_t)i * DD + u] = tanhf(acc + bencv);
                    if (u == 0) state[i] = 2;   // node done; visible next round
                }
            }
        }
        grid_barrier(ctrl, bgrp, ++bnum);
        ++r;
    }
}

extern "C" void kernel_launch(void* const* d_in, const int* in_sizes, int n_in,
                              void* d_out, int out_size, void* d_ws, size_t ws_size,
                              hipStream_t stream) {
    hipMemsetAsync(d_ws, 0, WS_ZERO_BYTES, stream);
    tree_lstm_kernel<<<dim3(NB), dim3(TPB), 0, stream>>>(
        (const float*)d_in[0],
        (const float*)d_in[1], (const float*)d_in[2],
        (const float*)d_in[3], (const float*)d_in[4],
        (const float*)d_in[5], (const float*)d_in[6],
        (const float*)d_in[7], (const float*)d_in[8],
        (const float*)d_in[9], (const float*)d_in[10],
        (const int*)d_in[11], (const int*)d_in[12],
        (float*)d_out, (char*)d_ws);
}